// Round 7
// baseline (255.008 us; speedup 1.0000x reference)
//
#include <hip/hip_runtime.h>

#define NVOX 150000
#define BM 64
#define MTILES 2344         // ceil(150000/64)
#define SROW 150016         // column stride of h buffer
#define NCOL 320

typedef __attribute__((ext_vector_type(8))) short bf16x8;
typedef __attribute__((ext_vector_type(4))) float f32x4;
typedef __attribute__((ext_vector_type(4))) unsigned short us4;

__device__ __forceinline__ unsigned short f2bf(float f) {
    unsigned u = __builtin_bit_cast(unsigned, f);
    u += 0x7fffu + ((u >> 16) & 1u);
    return (unsigned short)(u >> 16);
}

__device__ __forceinline__ void gld16(const void* g, void* l) {
    __builtin_amdgcn_global_load_lds(
        (const __attribute__((address_space(1))) unsigned int*)g,
        (__attribute__((address_space(3))) unsigned int*)l, 16, 0, 0);
}

// ---------------- prep: features f32 -> bf16, x8 vectorized (+ zero row) ----------------
__global__ void prep_feat(const float* __restrict__ src, unsigned short* __restrict__ dst) {
    int i = blockIdx.x * 256 + threadIdx.x;
    if (i < NVOX * 8) {
        const float4 a = *(const float4*)(src + (size_t)i * 8);
        const float4 b = *(const float4*)(src + (size_t)i * 8 + 4);
        us4 lo, hi;
        lo.x = f2bf(a.x); lo.y = f2bf(a.y); lo.z = f2bf(a.z); lo.w = f2bf(a.w);
        hi.x = f2bf(b.x); hi.y = f2bf(b.y); hi.z = f2bf(b.z); hi.w = f2bf(b.w);
        *(us4*)(dst + (size_t)i * 8) = lo;
        *(us4*)(dst + (size_t)i * 8 + 4) = hi;
    } else if (i < NVOX * 8 + 8) {
        us4 z; z.x = 0; z.y = 0; z.z = 0; z.w = 0;
        *(us4*)(dst + (size_t)i * 8) = z;   // zero row for invalid/pad gathers
    }
}

// ---- prep: W3[h][kk][c][o] -> fragment-packed Bf[(kk*5+h)][ks*4+nt][lane][e] bf16 ----
// value = W3[h][kk][c = ks*32 + (lane>>4)*8 + e][o = nt*16 + (lane&15)]
__global__ void prep_w3(const float* __restrict__ w3, unsigned short* __restrict__ bf,
                        float* __restrict__ stats) {
    __shared__ float tile[64 * 65];
    int b = blockIdx.x;            // b = h*9+kk, 45 blocks
    int tid = threadIdx.x;
    const float* src = w3 + (size_t)b * 4096;
#pragma unroll
    for (int t = 0; t < 16; ++t) {
        int lin = t * 256 + tid;   // c = lin>>6, o = lin&63  (coalesced read over o)
        tile[(lin >> 6) * 65 + (lin & 63)] = src[lin];
    }
    __syncthreads();
    int h = b / 9, kk = b - h * 9;
    unsigned short* dst = bf + (size_t)(kk * 5 + h) * 4096;
#pragma unroll
    for (int t = 0; t < 16; ++t) {
        int lin = t * 256 + tid;          // 4096 elements of this (kk,h) region
        int e = lin & 7;
        int lane = (lin >> 3) & 63;
        int t2 = lin >> 9;                // 0..7: nt = t2&3, ks = t2>>2
        int c = (t2 >> 2) * 32 + (lane >> 4) * 8 + e;
        int o = (t2 & 3) * 16 + (lane & 15);
        dst[lin] = f2bf(tile[c * 65 + o]);
    }
    if (b == 0) for (int j = tid; j < 2 * NCOL; j += 256) stats[j] = 0.f;
}

// ---------------- gather-GEMM: BM=64, 5 waves, wave = one head (64x64 tile, acc=64).
// A gathered ONCE per block (chunk-major global_load_lds dbuf), reused by all 5 waves.
// B fragment-packed global->reg. 32 MFMA per wave per staging phase; ~128 regs/wave. ----
__global__ __launch_bounds__(320, 4)
void gemm_kernel(const unsigned short* __restrict__ featB,
                 const unsigned short* __restrict__ Bf,
                 const int* __restrict__ nbr,
                 unsigned short* __restrict__ hbuf,
                 float* __restrict__ stats) {
    __shared__ __align__(16) char smem[18688];
    constexpr int IDX_OFF = 16384;   // 9*64 int byte-offsets (2304 B)

    int mtile = blockIdx.x;
    int m0 = mtile * BM;
    int tid = threadIdx.x;
    int w = tid >> 6, lane = tid & 63;     // w = head index
    int quad = lane >> 4, m16 = lane & 15;
    int* sIdx = (int*)(smem + IDX_OFF);

    // ---- stage neighbor byte-offset table: sIdx[kk*64 + row] = srow*128 ----
    for (int lin = tid; lin < 576; lin += 320) {
        int v = (m0 * 9 + lin < NVOX * 9) ? nbr[(size_t)m0 * 9 + lin] : -1;
        int row = lin / 9, kkq = lin - row * 9;
        sIdx[kkq * 64 + row] = ((v < 0) ? NVOX : v) * 128;
    }
    __syncthreads();

    f32x4 acc[4][4];
#pragma unroll
    for (int mt = 0; mt < 4; ++mt)
#pragma unroll
        for (int nt = 0; nt < 4; ++nt)
            acc[mt][nt] = (f32x4){0.f, 0.f, 0.f, 0.f};

    const char* fb = (const char*)featB;
    const char* bq = (const char*)Bf + (size_t)w * 8192 + lane * 16;  // head base

// A staging: waves 0-3 own chunks {2w,2w+1}; dbuf = kk&1; dst wave-uniform + lane*16
#define STAGE(kkx)                                                              \
    do {                                                                        \
        if (w < 4) {                                                            \
            int off = sIdx[(kkx) * 64 + lane];                                  \
            char* dstS = smem + ((kkx) & 1) * 8192;                             \
            gld16(fb + off + (w * 2) * 16, dstS + (w * 2) * 1024);              \
            gld16(fb + off + (w * 2 + 1) * 16, dstS + (w * 2 + 1) * 1024);      \
        }                                                                       \
    } while (0)

    STAGE(0);
#pragma unroll
    for (int kk = 0; kk < 9; ++kk) {
        __syncthreads();   // buf[kk&1] staged (each wave drains own vmcnt) + prev reads done
        const char* cur = smem + (kk & 1) * 8192;
        // B both ks loaded BEFORE the stage gld16s (vmcnt FIFO: prefetch stays in flight)
        bf16x8 b0[4], b1[4];
#pragma unroll
        for (int nt = 0; nt < 4; ++nt)
            b0[nt] = *(const bf16x8*)(bq + (kk * 5) * 8192 + (0 * 4 + nt) * 1024);
#pragma unroll
        for (int nt = 0; nt < 4; ++nt)
            b1[nt] = *(const bf16x8*)(bq + (kk * 5) * 8192 + (1 * 4 + nt) * 1024);
        if (kk < 8) STAGE(kk + 1);   // covered by the 32 MFMAs below + barrier slack
        {
            bf16x8 af[4];
#pragma unroll
            for (int mt = 0; mt < 4; ++mt)
                af[mt] = *(const bf16x8*)(cur + quad * 1024 + (mt * 16 + m16) * 16);
#pragma unroll
            for (int mt = 0; mt < 4; ++mt)
#pragma unroll
                for (int nt = 0; nt < 4; ++nt)
                    acc[mt][nt] = __builtin_amdgcn_mfma_f32_16x16x32_bf16(
                        af[mt], b0[nt], acc[mt][nt], 0, 0, 0);
        }
        {
            bf16x8 af[4];
#pragma unroll
            for (int mt = 0; mt < 4; ++mt)
                af[mt] = *(const bf16x8*)(cur + (4 + quad) * 1024 + (mt * 16 + m16) * 16);
#pragma unroll
            for (int mt = 0; mt < 4; ++mt)
#pragma unroll
                for (int nt = 0; nt < 4; ++nt)
                    acc[mt][nt] = __builtin_amdgcn_mfma_f32_16x16x32_bf16(
                        af[mt], b1[nt], acc[mt][nt], 0, 0, 0);
        }
    }
#undef STAGE
    __syncthreads();   // K-loop LDS dead; alias for epilogue

    // ---- epilogue: 5 sequential head phases; LDS transpose -> full-line column stores ----
    unsigned short* sOut = (unsigned short*)smem;   // 64 cols x 136 ushorts = 17408 B
#pragma unroll
    for (int h = 0; h < 5; ++h) {
        if (w == h) {
#pragma unroll
            for (int mt = 0; mt < 4; ++mt)
#pragma unroll
                for (int nt = 0; nt < 4; ++nt) {
                    int col = nt * 16 + m16;
                    int row = mt * 16 + quad * 4;
                    f32x4 v = acc[mt][nt];
                    unsigned lo = (unsigned)f2bf(v.x) | ((unsigned)f2bf(v.y) << 16);
                    unsigned hi = (unsigned)f2bf(v.z) | ((unsigned)f2bf(v.w) << 16);
                    uint2 pk; pk.x = lo; pk.y = hi;
                    *(uint2*)(sOut + col * 136 + row) = pk;
                }
        }
        __syncthreads();
        if (tid < 256) {
#pragma unroll
            for (int it = 0; it < 2; ++it) {
                int s = it * 256 + tid;        // 512 slots: 64 cols x 8 x uint4
                int col = s >> 3, l8 = s & 7;
                uint4 v = *(const uint4*)(sOut + col * 136 + l8 * 8);
                *(uint4*)(hbuf + (size_t)(h * 64 + col) * SROW + m0 + l8 * 8) = v;
            }
        }
        __syncthreads();
    }

    // ---- BN statistics (pad/invalid rows are exact zeros): in-wave reduce + atomics ----
    {
        float s[4], ss[4];
#pragma unroll
        for (int nt = 0; nt < 4; ++nt) {
            float a = 0.f, b = 0.f;
#pragma unroll
            for (int mt = 0; mt < 4; ++mt) {
                f32x4 v = acc[mt][nt];
                a += v.x + v.y + v.z + v.w;
                b += v.x * v.x + v.y * v.y + v.z * v.z + v.w * v.w;
            }
            s[nt] = a; ss[nt] = b;
            s[nt] += __shfl_xor(s[nt], 16); s[nt] += __shfl_xor(s[nt], 32);
            ss[nt] += __shfl_xor(ss[nt], 16); ss[nt] += __shfl_xor(ss[nt], 32);
        }
        if (quad == 0) {
#pragma unroll
            for (int nt = 0; nt < 4; ++nt) {
                atomicAdd(&stats[w * 64 + nt * 16 + m16], s[nt]);
                atomicAdd(&stats[NCOL + w * 64 + nt * 16 + m16], ss[nt]);
            }
        }
    }
}

// ------- pass 2: BN + ReLU + 1x1 conv; thread = (row-pair, head), h wave-uniform -------
__global__ void head_kernel(const unsigned short* __restrict__ hbuf,
                            const float* __restrict__ stats,
                            const float* __restrict__ gamma, const float* __restrict__ beta,
                            const float* __restrict__ W1_0, const float* __restrict__ W1_1,
                            const float* __restrict__ W1_2, const float* __restrict__ W1_3,
                            const float* __restrict__ W1_4,
                            const float* __restrict__ b1_0, const float* __restrict__ b1_1,
                            const float* __restrict__ b1_2, const float* __restrict__ b1_3,
                            const float* __restrict__ b1_4,
                            float* __restrict__ out) {
    __shared__ float sScale[NCOL], sShift[NCOL], sW1[NCOL * 3], sB1[16];
    int tid = threadIdx.x;
    for (int c = tid; c < NCOL; c += 256) {
        float mean = stats[c] * (1.f / (float)NVOX);
        float var = stats[NCOL + c] * (1.f / (float)NVOX) - mean * mean;
        float inv = rsqrtf(var + 1e-5f);
        float sc = inv * gamma[c];
        sScale[c] = sc;
        sShift[c] = beta[c] - mean * sc;
    }
    for (int i = tid; i < 192; i += 256) { int cc = i / 3, jj = i - cc * 3; sW1[0 * 192 + i] = W1_0[cc * 3 + jj]; }
    for (int i = tid; i < 192; i += 256) { int cc = i / 3, jj = i - cc * 3; sW1[1 * 192 + i] = (jj < 2) ? W1_1[cc * 2 + jj] : 0.f; }
    for (int i = tid; i < 192; i += 256) { int cc = i / 3, jj = i - cc * 3; sW1[2 * 192 + i] = (jj < 1) ? W1_2[cc] : 0.f; }
    for (int i = tid; i < 192; i += 256) { int cc = i / 3, jj = i - cc * 3; sW1[3 * 192 + i] = W1_3[cc * 3 + jj]; }
    for (int i = tid; i < 192; i += 256) { int cc = i / 3, jj = i - cc * 3; sW1[4 * 192 + i] = (jj < 2) ? W1_4[cc * 2 + jj] : 0.f; }
    if (tid == 0) {
        sB1[0] = b1_0[0]; sB1[1] = b1_0[1]; sB1[2] = b1_0[2];
        sB1[3] = b1_1[0]; sB1[4] = b1_1[1]; sB1[5] = 0.f;
        sB1[6] = b1_2[0]; sB1[7] = 0.f;    sB1[8] = 0.f;
        sB1[9] = b1_3[0]; sB1[10] = b1_3[1]; sB1[11] = b1_3[2];
        sB1[12] = b1_4[0]; sB1[13] = b1_4[1]; sB1[14] = 0.f;
    }
    __syncthreads();
    int lin = blockIdx.x * 256 + tid;     // 5 heads x 75008 row-pairs (wave-aligned)
    int h = lin / 75008;
    int rp = lin - h * 75008;
    if (rp >= 75000) return;
    int n = rp * 2;                       // rows n, n+1
    const unsigned short* hp = hbuf + n;
    float x0 = sB1[h * 3 + 0], x1 = sB1[h * 3 + 1], x2 = sB1[h * 3 + 2];
    float y0 = x0, y1 = x1, y2 = x2;
    int cbase = h * 64;
#pragma unroll 16
    for (int cc = 0; cc < 64; ++cc) {
        int c = cbase + cc;
        unsigned raw = *(const unsigned*)(hp + (size_t)c * SROW);
        float v0 = __builtin_bit_cast(float, raw << 16);
        float v1 = __builtin_bit_cast(float, raw & 0xffff0000u);
        float sc = sScale[c], sh = sShift[c];
        v0 = fmaxf(v0 * sc + sh, 0.f);
        v1 = fmaxf(v1 * sc + sh, 0.f);
        float w0 = sW1[c * 3 + 0], w1 = sW1[c * 3 + 1], w2 = sW1[c * 3 + 2];
        x0 += v0 * w0; x1 += v0 * w1; x2 += v0 * w2;
        y0 += v1 * w0; y1 += v1 * w1; y2 += v1 * w2;
    }
    if (h == 0) {
        out[n * 3 + 0] = x0; out[n * 3 + 1] = x1; out[n * 3 + 2] = x2;
        out[(n + 1) * 3 + 0] = y0; out[(n + 1) * 3 + 1] = y1; out[(n + 1) * 3 + 2] = y2;
    } else if (h == 1) {
        out[450000 + n * 2 + 0] = x0; out[450000 + n * 2 + 1] = x1;
        out[450000 + (n + 1) * 2 + 0] = y0; out[450000 + (n + 1) * 2 + 1] = y1;
    } else if (h == 2) {
        out[750000 + n] = x0; out[750000 + n + 1] = y0;
    } else if (h == 3) {
        out[900000 + n * 3 + 0] = x0; out[900000 + n * 3 + 1] = x1; out[900000 + n * 3 + 2] = x2;
        out[900000 + (n + 1) * 3 + 0] = y0; out[900000 + (n + 1) * 3 + 1] = y1; out[900000 + (n + 1) * 3 + 2] = y2;
    } else {
        out[1350000 + n * 2 + 0] = x0; out[1350000 + n * 2 + 1] = x1;
        out[1350000 + (n + 1) * 2 + 0] = y0; out[1350000 + (n + 1) * 2 + 1] = y1;
    }
}

extern "C" void kernel_launch(void* const* d_in, const int* in_sizes, int n_in,
                              void* d_out, int out_size, void* d_ws, size_t ws_size,
                              hipStream_t stream) {
    const float* features = (const float*)d_in[0];
    const int* nbr        = (const int*)d_in[1];
    const float* w3       = (const float*)d_in[2];
    const float* gamma    = (const float*)d_in[3];
    const float* beta     = (const float*)d_in[4];
    const float* W1_0 = (const float*)d_in[5];  const float* b1_0 = (const float*)d_in[6];
    const float* W1_1 = (const float*)d_in[7];  const float* b1_1 = (const float*)d_in[8];
    const float* W1_2 = (const float*)d_in[9];  const float* b1_2 = (const float*)d_in[10];
    const float* W1_3 = (const float*)d_in[11]; const float* b1_3 = (const float*)d_in[12];
    const float* W1_4 = (const float*)d_in[13]; const float* b1_4 = (const float*)d_in[14];
    float* out = (float*)d_out;

    char* ws = (char*)d_ws;
    unsigned short* featB = (unsigned short*)ws;               // (150000+1)*64 bf16
    unsigned short* Bf    = (unsigned short*)(ws + 19200128);  // 45*4096 bf16 = 368,640 B
    float* stats          = (float*)(ws + 19568768);           // 640 f32
    unsigned short* hbuf  = (unsigned short*)(ws + 19571328);  // 320*150016 bf16

    prep_feat<<<(NVOX * 8 + 8 + 255) / 256, 256, 0, stream>>>(features, featB);
    prep_w3<<<45, 256, 0, stream>>>(w3, Bf, stats);
    gemm_kernel<<<MTILES, 320, 0, stream>>>(featB, Bf, nbr, hbuf, stats);
    head_kernel<<<(5 * 75008) / 256, 256, 0, stream>>>(hbuf, stats, gamma, beta,
        W1_0, W1_1, W1_2, W1_3, W1_4, b1_0, b1_1, b1_2, b1_3, b1_4, out);
}